// Round 23
// baseline (433.710 us; speedup 1.0000x reference)
//
#include <hip/hip_runtime.h>
#include <math.h>

// ---------------------------------------------------------------------------
// GraphConv (2-layer GAT) pipeline.
// GEMMs: split-bf16 MFMA (fp32 = hi+lo bf16 RNE pair along K, K'=2K),
//   non-temporal A loads (R19), fp16 h intermediate (R20). Tile 128x128,
//   BK=32, 512 threads = 2x4 waves of 64x32, dbuf LDS 64KB (R22 = 427.8us).
// R23: A-prefetch ring deepened to 3 steps ahead. Model: upscale is HBM
//   latency-capacity bound on the nt A-stream (dur = FETCH/1.9TB/s, ~2
//   in-flight loads/wave). r1,r2,r3 rotate: issue A(ks+3) while consuming
//   A(ks+1) -> ~3x in-flight bytes. Tail clamped loads never consumed.
// ---------------------------------------------------------------------------

typedef __attribute__((ext_vector_type(8))) short bf16x8;
typedef __attribute__((ext_vector_type(4))) float f32x4;

__device__ __forceinline__ float gelu_exact(float x) {
    return 0.5f * x * (1.0f + erff(x * 0.70710678118654752f));
}

__device__ __forceinline__ unsigned int rne_bf16_bits(float f) {
    unsigned int u = __float_as_uint(f);
    unsigned int r = u + 0x7FFFu + ((u >> 16) & 1u);
    return r & 0xFFFF0000u;
}

// fp32 -> packed (hi bf16 | lo bf16<<16), RNE split.
__device__ __forceinline__ unsigned int packsplit(float f) {
    unsigned int hi_bits = rne_bf16_bits(f);
    float resid = f - __uint_as_float(hi_bits);
    unsigned int lo_bits = rne_bf16_bits(resid);
    return (hi_bits >> 16) | lo_bits;
}

__device__ __forceinline__ float h2f(ushort u) {
    _Float16 h;
    __builtin_memcpy(&h, &u, 2);
    return (float)h;
}
__device__ __forceinline__ ushort f2h(float f) {
    _Float16 h = (_Float16)f;
    ushort u;
    __builtin_memcpy(&u, &h, 2);
    return u;
}

// ---------------------------------------------------------------------------
// conv_all: all 4 weight matrices -> pre-swizzled Bt tiles in ONE launch.
// ---------------------------------------------------------------------------
__global__ void conv_all(const float* __restrict__ Wimg, const float* __restrict__ Wtxt,
                         const float* __restrict__ Wl0,  const float* __restrict__ Wl1,
                         ushort* __restrict__ BtImg, ushort* __restrict__ BtTxt,
                         ushort* __restrict__ BtW0,  ushort* __restrict__ BtW1)
{
    int t = blockIdx.x * 256 + threadIdx.x;
    const float* W; ushort* Bt; int K, Bcols;
    if (t < 24576)      { W = Wimg; Bt = BtImg; K = 768; Bcols = 128; }
    else if (t < 49152) { W = Wtxt; Bt = BtTxt; K = 768; Bcols = 128; t -= 24576; }
    else if (t < 65536) { W = Wl0;  Bt = BtW0;  K = 256; Bcols = 256; t -= 49152; }
    else if (t < 81920) { W = Wl1;  Bt = BtW1;  K = 256; Bcols = 256; t -= 65536; }
    else return;
    int KS = K >> 5;
    int kg    = t & 7;
    int col   = (t >> 3) & 127;
    int rest  = t >> 10;
    int kstep = rest % KS;
    int ct    = rest / KS;
    int gcol  = ct * 128 + col;
    int kbase = kstep * 32 + kg * 4;
    uint4 v;
    v.x = packsplit(W[(size_t)(kbase + 0) * Bcols + gcol]);
    v.y = packsplit(W[(size_t)(kbase + 1) * Bcols + gcol]);
    v.z = packsplit(W[(size_t)(kbase + 2) * Bcols + gcol]);
    v.w = packsplit(W[(size_t)(kbase + 3) * Bcols + gcol]);
    size_t tile = (size_t)(ct * KS + kstep) * 8192;
    *(uint4*)&Bt[tile + col * 64 + ((kg * 8) ^ ((col & 7) << 3))] = v;
}

// ---------------------------------------------------------------------------
// Split-bf16 MFMA GEMM, tile 128x128, BK=32, 8 waves (2x4 of 64x32), dbuf.
// A loads NON-TEMPORAL, 3-deep prefetch ring.
// MODE=0 (layer): C is ushort* (fp16 h). MODE=1 (upscale): fp32 gelu scatter.
// ---------------------------------------------------------------------------
template<int MODE>
__global__ __launch_bounds__(512)
void gemm128(const float* __restrict__ A0, const float* __restrict__ A1,
             const ushort* __restrict__ B0, const ushort* __restrict__ B1,
             const float* __restrict__ bias0, const float* __restrict__ bias1,
             float* __restrict__ C, const int* __restrict__ ci,
             int M, int K, int cb0, int cb1)
{
    __shared__ ushort As[2][128 * 64];    // 16KB per buffer
    __shared__ ushort Bs[2][128 * 64];    // 16KB per buffer

    const int tid  = threadIdx.x;
    const int lane = tid & 63;
    const int w    = tid >> 6;            // 0..7
    const int wr   = w >> 2, wc = w & 3;  // wave -> 64x32 quadrant
    const int row0 = blockIdx.x * 128;
    const int KS   = K >> 5;

    const float* A; const ushort* Btile; const float* bias; int col_base, colt;
    if (MODE == 1) {
        int sel = blockIdx.y;
        A = sel ? A1 : A0; Btile = sel ? B1 : B0;
        bias = sel ? bias1 : bias0; col_base = sel ? cb1 : cb0; colt = 0;
    } else {
        A = A0; Btile = B0 + (size_t)blockIdx.y * KS * 8192;
        bias = nullptr; col_base = 0; colt = blockIdx.y * 128;
    }

    const int ar0 = tid >> 3;             // A row (p=0): 0..63
    const int ac4 = (tid & 7) * 4;        // A fp32 col within step

    f32x4 acc[4][2];
#pragma unroll
    for (int m = 0; m < 4; m++)
#pragma unroll
        for (int n = 0; n < 2; n++) acc[m][n] = (f32x4)0.f;

    auto loadA = [&](f32x4* rg, int ks) {
        int kk = ks < KS ? ks : KS - 1;   // clamp: tail loads never consumed
#pragma unroll
        for (int p = 0; p < 2; p++) {
            int gr = row0 + ar0 + p * 64;
            rg[p] = (f32x4)0.f;
            if (gr < M)
                rg[p] = __builtin_nontemporal_load(
                    (const f32x4*)&A[(size_t)gr * K + kk * 32 + ac4]);
        }
    };
    auto writeA = [&](int buf, const f32x4* rg) {
#pragma unroll
        for (int p = 0; p < 2; p++) {
            int r = ar0 + p * 64;
            uint4 wv;
            wv.x = packsplit(rg[p][0]); wv.y = packsplit(rg[p][1]);
            wv.z = packsplit(rg[p][2]); wv.w = packsplit(rg[p][3]);
            *(uint4*)&As[buf][r * 64 + ((2 * ac4) ^ ((r & 7) << 3))] = wv;
        }
    };
    auto stageB = [&](int buf, int ks) {
        const ushort* tp = Btile + (size_t)ks * 8192;
#pragma unroll
        for (int q = 0; q < 2; q++) {
            int off = (w * 2 + q) * 512;          // ushorts; 1KB per call
            __builtin_amdgcn_global_load_lds(
                (const __attribute__((address_space(1))) void*)(tp + off + lane * 8),
                (__attribute__((address_space(3))) void*)(&Bs[buf][off]),
                16, 0, 0);
        }
    };
    auto compute = [&](int buf) {
        bf16x8 af[4][2], bfr[2][2];
#pragma unroll
        for (int m = 0; m < 4; m++) {
            int row = wr * 64 + m * 16 + (lane & 15);
#pragma unroll
            for (int kb = 0; kb < 2; kb++) {
                int kp = kb * 32 + (lane >> 4) * 8;
                af[m][kb] = *(const bf16x8*)&As[buf][row * 64 + (kp ^ ((row & 7) << 3))];
            }
        }
#pragma unroll
        for (int n = 0; n < 2; n++) {
            int cq = wc * 32 + n * 16 + (lane & 15);
#pragma unroll
            for (int kb = 0; kb < 2; kb++) {
                int kp = kb * 32 + (lane >> 4) * 8;
                bfr[n][kb] = *(const bf16x8*)&Bs[buf][cq * 64 + (kp ^ ((cq & 7) << 3))];
            }
        }
#pragma unroll
        for (int m = 0; m < 4; m++)
#pragma unroll
            for (int n = 0; n < 2; n++) {
                acc[m][n] = __builtin_amdgcn_mfma_f32_16x16x32_bf16(
                    af[m][0], bfr[n][0], acc[m][n], 0, 0, 0);
                acc[m][n] = __builtin_amdgcn_mfma_f32_16x16x32_bf16(
                    af[m][1], bfr[n][1], acc[m][n], 0, 0, 0);
            }
    };

    // prologue: fill buffer 0; prefetch A(1), A(2)
    f32x4 rt[2], r1[2], r2[2];
    loadA(rt, 0);
    stageB(0, 0);
    writeA(0, rt);
    loadA(r1, 1);
    loadA(r2, 2);
    __syncthreads();

    int cur = 0;
    for (int ks = 0; ks < KS - 1; ++ks) {
        int nxt = cur ^ 1;
        stageB(nxt, ks + 1);                  // async B into other buffer
        f32x4 r3[2];
        loadA(r3, ks + 3);                    // 3 steps ahead (clamped at tail)
        writeA(nxt, r1);                      // consume A(ks+1)
        compute(cur);
        __syncthreads();
        r1[0] = r2[0]; r1[1] = r2[1];
        r2[0] = r3[0]; r2[1] = r3[1];
        cur = nxt;
    }
    compute(cur);

    // epilogue: C/D layout col=lane&15, row=(lane>>4)*4+reg
    ushort* C16 = (ushort*)C;
#pragma unroll
    for (int m = 0; m < 4; m++) {
        int rbase = row0 + wr * 64 + m * 16 + ((lane >> 4) << 2);
#pragma unroll
        for (int n = 0; n < 2; n++) {
            int col = wc * 32 + n * 16 + (lane & 15);
#pragma unroll
            for (int j = 0; j < 4; j++) {
                int grow = rbase + j;
                if (grow >= M) continue;
                float v = acc[m][n][j];
                if (MODE == 1) {
                    v = gelu_exact(v + bias[col]);
                    C[(size_t)ci[grow] * 256 + col_base + col] = v;
                } else {
                    C16[(size_t)grow * 256 + colt + col] = f2h(v);
                }
            }
        }
    }
}

// per-node attention scores (fp16 h input)
__global__ __launch_bounds__(256)
void scores_kernel(const ushort* __restrict__ h16, const float* __restrict__ asrc,
                   const float* __restrict__ adst, float* __restrict__ s_src,
                   float* __restrict__ s_dst, int N)
{
    int wave = threadIdx.x >> 6;
    int lane = threadIdx.x & 63;
    int n = blockIdx.x * 4 + wave;
    if (n >= N) return;
    ushort4 hv = *(const ushort4*)&h16[(size_t)n * 256 + lane * 4];
    float x0 = h2f(hv.x), x1 = h2f(hv.y), x2 = h2f(hv.z), x3 = h2f(hv.w);
    float4 av = *(const float4*)&asrc[lane * 4];
    float4 dv = *(const float4*)&adst[lane * 4];
    float ps = x0 * av.x + x1 * av.y + x2 * av.z + x3 * av.w;
    float pd = x0 * dv.x + x1 * dv.y + x2 * dv.z + x3 * dv.w;
#pragma unroll
    for (int off = 32; off; off >>= 1) {
        ps += __shfl_xor(ps, off);
        pd += __shfl_xor(pd, off);
    }
    if (lane == 0) { s_src[n] = ps; s_dst[n] = pd; }
}

// ---- CSR build (5 launches) ----
__global__ void count_edges(const int* __restrict__ edges, int* cnt, int E) {
    int e = blockIdx.x * 256 + threadIdx.x;
    if (e < E) atomicAdd(&cnt[edges[2 * e + 1]], 1);
}

__global__ void scan1(const int* __restrict__ cnt, int* __restrict__ rs,
                      int* __restrict__ bsum, int N)
{
    __shared__ int sm[256];
    int tid = threadIdx.x;
    int i = blockIdx.x * 256 + tid;
    int v = (i < N) ? (cnt[i] + 1) : 0;
    sm[tid] = v;
    __syncthreads();
    for (int off = 1; off < 256; off <<= 1) {
        int t = (tid >= off) ? sm[tid - off] : 0;
        __syncthreads();
        sm[tid] += t;
        __syncthreads();
    }
    if (i < N) rs[i] = sm[tid] - v;
    if (tid == 255) bsum[blockIdx.x] = sm[255];
}

__global__ void scan2(int* bsum, int nb) {
    __shared__ int sm[256];
    int tid = threadIdx.x;
    int v = (tid < nb) ? bsum[tid] : 0;
    sm[tid] = v;
    __syncthreads();
    for (int off = 1; off < 256; off <<= 1) {
        int t = (tid >= off) ? sm[tid - off] : 0;
        __syncthreads();
        sm[tid] += t;
        __syncthreads();
    }
    if (tid < nb) bsum[tid] = sm[tid] - v;
}

__global__ void scan3(int* __restrict__ rs, const int* __restrict__ bsum,
                      int* __restrict__ cur, int N, int total)
{
    int i = blockIdx.x * 256 + threadIdx.x;
    if (i < N) {
        int v = rs[i] + bsum[i >> 8];
        rs[i] = v;
        cur[i] = v;
    }
    if (i == 0) rs[N] = total;
}

__global__ void fill_csr(const int* __restrict__ edges, int* __restrict__ cur,
                         int* __restrict__ col, int E, int N)
{
    int i = blockIdx.x * 256 + threadIdx.x;
    if (i < E) {
        int s = edges[2 * i], d = edges[2 * i + 1];
        col[atomicAdd(&cur[d], 1)] = s;
    } else if (i < E + N) {
        int n = i - E;
        col[atomicAdd(&cur[n], 1)] = n;
    }
}

// ---------------------------------------------------------------------------
// attn: WAVE per dst node. No LDS, no barriers. fp16 h gather (ushort4/lane).
// ---------------------------------------------------------------------------
template<int EPI>
__global__ __launch_bounds__(256)
void attn_kernel(const ushort* __restrict__ h16, const float* __restrict__ s_src,
                 const float* __restrict__ s_dst, const int* __restrict__ rs,
                 const int* __restrict__ colv, const float* __restrict__ bias,
                 float* __restrict__ out, int N)
{
    const int wv   = threadIdx.x >> 6;
    const int lane = threadIdx.x & 63;
    const int n    = blockIdx.x * 4 + wv;
    if (n >= N) return;

    const float sd = s_dst[n];
    const int beg = rs[n], end = rs[n + 1];

    float4 acc = make_float4(0.f, 0.f, 0.f, 0.f);
    float den = 0.f;

    int i = beg;
    for (; i + 3 < end; i += 4) {
        int s0 = colv[i], s1 = colv[i + 1], s2 = colv[i + 2], s3 = colv[i + 3];
        float e0 = s_src[s0] + sd, e1 = s_src[s1] + sd;
        float e2 = s_src[s2] + sd, e3 = s_src[s3] + sd;
        e0 = (e0 > 0.f) ? e0 : 0.2f * e0;  e1 = (e1 > 0.f) ? e1 : 0.2f * e1;
        e2 = (e2 > 0.f) ? e2 : 0.2f * e2;  e3 = (e3 > 0.f) ? e3 : 0.2f * e3;
        float w0 = __expf(e0), w1 = __expf(e1), w2 = __expf(e2), w3 = __expf(e3);
        ushort4 u0 = *(const ushort4*)&h16[(size_t)s0 * 256 + lane * 4];
        ushort4 u1 = *(const ushort4*)&h16[(size_t)s1 * 256 + lane * 4];
        ushort4 u2 = *(const ushort4*)&h16[(size_t)s2 * 256 + lane * 4];
        ushort4 u3 = *(const ushort4*)&h16[(size_t)s3 * 256 + lane * 4];
        acc.x = fmaf(w0, h2f(u0.x), acc.x); acc.y = fmaf(w0, h2f(u0.y), acc.y);
        acc.z = fmaf(w0, h2f(u0.z), acc.z); acc.w = fmaf(w0, h2f(u0.w), acc.w);
        acc.x = fmaf(w1, h2f(u1.x), acc.x); acc.y = fmaf(w1, h2f(u1.y), acc.y);
        acc.z = fmaf(w1, h2f(u1.z), acc.z); acc.w = fmaf(w1, h2f(u1.w), acc.w);
        acc.x = fmaf(w2, h2f(u2.x), acc.x); acc.y = fmaf(w2, h2f(u2.y), acc.y);
        acc.z = fmaf(w2, h2f(u2.z), acc.z); acc.w = fmaf(w2, h2f(u2.w), acc.w);
        acc.x = fmaf(w3, h2f(u3.x), acc.x); acc.y = fmaf(w3, h2f(u3.y), acc.y);
        acc.z = fmaf(w3, h2f(u3.z), acc.z); acc.w = fmaf(w3, h2f(u3.w), acc.w);
        den += w0 + w1 + w2 + w3;
    }
    for (; i < end; ++i) {
        int s0 = colv[i];
        float e0 = s_src[s0] + sd;
        e0 = (e0 > 0.f) ? e0 : 0.2f * e0;
        float w0 = __expf(e0);
        ushort4 u0 = *(const ushort4*)&h16[(size_t)s0 * 256 + lane * 4];
        acc.x = fmaf(w0, h2f(u0.x), acc.x); acc.y = fmaf(w0, h2f(u0.y), acc.y);
        acc.z = fmaf(w0, h2f(u0.z), acc.z); acc.w = fmaf(w0, h2f(u0.w), acc.w);
        den += w0;
    }

    float4 bv = *(const float4*)&bias[lane * 4];
    float inv = 1.f / den;
    float4 v;
    v.x = acc.x * inv + bv.x; v.y = acc.y * inv + bv.y;
    v.z = acc.z * inv + bv.z; v.w = acc.w * inv + bv.w;
    if (EPI == 1) {
        v.x = gelu_exact(v.x); v.y = gelu_exact(v.y);
        v.z = gelu_exact(v.z); v.w = gelu_exact(v.w);
    } else {
        v.x = fmaxf(v.x, 0.f); v.y = fmaxf(v.y, 0.f);
        v.z = fmaxf(v.z, 0.f); v.w = fmaxf(v.w, 0.f);
    }
    *(float4*)&out[(size_t)n * 256 + lane * 4] = v;
}

extern "C" void kernel_launch(void* const* d_in, const int* in_sizes, int n_in,
                              void* d_out, int out_size, void* d_ws, size_t ws_size,
                              hipStream_t stream)
{
    const float* img    = (const float*)d_in[0];
    const float* txt    = (const float*)d_in[1];
    const int*   ci     = (const int*)d_in[2];
    const int*   edges  = (const int*)d_in[3];
    const float* w_img  = (const float*)d_in[4];
    const float* b_img  = (const float*)d_in[5];
    const float* w_text = (const float*)d_in[6];
    const float* b_text = (const float*)d_in[7];
    const float* W0     = (const float*)d_in[8];
    const float* asrc0  = (const float*)d_in[9];
    const float* adst0  = (const float*)d_in[10];
    const float* bias0  = (const float*)d_in[11];
    const float* W1     = (const float*)d_in[12];
    const float* asrc1  = (const float*)d_in[13];
    const float* adst1  = (const float*)d_in[14];
    const float* bias1  = (const float*)d_in[15];

    const int N = in_sizes[2];
    const int E = in_sizes[3] / 2;
    const int T = E + N;

    // workspace layout
    float*  fA  = (float*)d_ws;                    // node / attn0 out  N*256 f32
    float*  fB  = fA + (size_t)N * 256;            // h16 (ushort view) N*256
    float*  sS  = fB + (size_t)N * 256;            // N
    float*  sD  = sS + N;                          // N
    int*    rs  = (int*)(sD + N);                  // N+1
    int*    cur = rs + (N + 1);                    // N
    int*    col = cur + N;                         // E+N
    int*    bsum = col + T;                        // <=256
    uintptr_t bt0 = ((uintptr_t)(bsum + 256) + 63) & ~(uintptr_t)63;
    ushort* BtImg = (ushort*)bt0;                  // 24 tiles x 8192
    ushort* BtTxt = BtImg + 24 * 8192;
    ushort* BtW0  = BtTxt + 24 * 8192;             // 16 tiles x 8192
    ushort* BtW1  = BtW0  + 16 * 8192;
    ushort* h16 = (ushort*)fB;

    const int nb256 = (N + 255) / 256;
    const int nbT   = (T + 255) / 256;
    const int gm128 = (N + 127) / 128;             // 391

    conv_all<<<(81920 + 255) / 256, 256, 0, stream>>>(
        w_img, w_text, W0, W1, BtImg, BtTxt, BtW0, BtW1);

    (void)hipMemsetAsync(cur, 0, (size_t)N * sizeof(int), stream);

    // merged upscale GEMMs: node -> fA (fp32)
    gemm128<1><<<dim3(gm128, 2), 512, 0, stream>>>(
        img, txt, BtImg, BtTxt, b_img, b_text, fA, ci, N, 768, 0, 128);

    count_edges<<<(E + 255) / 256, 256, 0, stream>>>(edges, cur, E);
    scan1<<<nb256, 256, 0, stream>>>(cur, rs, bsum, N);
    scan2<<<1, 256, 0, stream>>>(bsum, nb256);
    scan3<<<nb256, 256, 0, stream>>>(rs, bsum, cur, N, T);
    fill_csr<<<nbT, 256, 0, stream>>>(edges, cur, col, E, N);

    // ---- layer 0: h16 <- fA @ W0 ; attn0 -> fA (node is dead) ----
    gemm128<0><<<dim3(gm128, 2), 512, 0, stream>>>(
        fA, nullptr, BtW0, nullptr, nullptr, nullptr, fB, nullptr, N, 256, 0, 0);
    scores_kernel<<<(N + 3) / 4, 256, 0, stream>>>(h16, asrc0, adst0, sS, sD, N);
    attn_kernel<0><<<(N + 3) / 4, 256, 0, stream>>>(h16, sS, sD, rs, col, bias0, fA, N);

    // ---- layer 1: h16 <- fA @ W1 ; attn1 -> d_out ----
    gemm128<0><<<dim3(gm128, 2), 512, 0, stream>>>(
        fA, nullptr, BtW1, nullptr, nullptr, nullptr, fB, nullptr, N, 256, 0, 0);
    scores_kernel<<<(N + 3) / 4, 256, 0, stream>>>(h16, asrc1, adst1, sS, sD, N);
    attn_kernel<1><<<(N + 3) / 4, 256, 0, stream>>>(h16, sS, sD, rs, col, bias1, (float*)d_out, N);
}

// Round 24
// 425.646 us; speedup vs baseline: 1.0189x; 1.0189x over previous
//
#include <hip/hip_runtime.h>
#include <math.h>

// ---------------------------------------------------------------------------
// GraphConv (2-layer GAT) pipeline.  == R22/R20 verbatim (best: 427.8us) ==
// GEMMs: split-bf16 MFMA (fp32 = hi+lo bf16 RNE pair along K, K'=2K),
//   non-temporal A loads (R19: L2-eviction fix), fp16 h intermediate (R20).
// R24: final revert of R23's 3-deep prefetch ring (433.7us: clamped tail
//   loads added 7MB FETCH with no extra overlap — the barrier bounds
//   effective depth). This is the locked-in best configuration.
// ---------------------------------------------------------------------------

typedef __attribute__((ext_vector_type(8))) short bf16x8;
typedef __attribute__((ext_vector_type(4))) float f32x4;

__device__ __forceinline__ float gelu_exact(float x) {
    return 0.5f * x * (1.0f + erff(x * 0.70710678118654752f));
}

__device__ __forceinline__ unsigned int rne_bf16_bits(float f) {
    unsigned int u = __float_as_uint(f);
    unsigned int r = u + 0x7FFFu + ((u >> 16) & 1u);
    return r & 0xFFFF0000u;
}

// fp32 -> packed (hi bf16 | lo bf16<<16), RNE split.
__device__ __forceinline__ unsigned int packsplit(float f) {
    unsigned int hi_bits = rne_bf16_bits(f);
    float resid = f - __uint_as_float(hi_bits);
    unsigned int lo_bits = rne_bf16_bits(resid);
    return (hi_bits >> 16) | lo_bits;
}

__device__ __forceinline__ float h2f(ushort u) {
    _Float16 h;
    __builtin_memcpy(&h, &u, 2);
    return (float)h;
}
__device__ __forceinline__ ushort f2h(float f) {
    _Float16 h = (_Float16)f;
    ushort u;
    __builtin_memcpy(&u, &h, 2);
    return u;
}

// ---------------------------------------------------------------------------
// conv_all: all 4 weight matrices -> pre-swizzled Bt tiles in ONE launch.
// ---------------------------------------------------------------------------
__global__ void conv_all(const float* __restrict__ Wimg, const float* __restrict__ Wtxt,
                         const float* __restrict__ Wl0,  const float* __restrict__ Wl1,
                         ushort* __restrict__ BtImg, ushort* __restrict__ BtTxt,
                         ushort* __restrict__ BtW0,  ushort* __restrict__ BtW1)
{
    int t = blockIdx.x * 256 + threadIdx.x;
    const float* W; ushort* Bt; int K, Bcols;
    if (t < 24576)      { W = Wimg; Bt = BtImg; K = 768; Bcols = 128; }
    else if (t < 49152) { W = Wtxt; Bt = BtTxt; K = 768; Bcols = 128; t -= 24576; }
    else if (t < 65536) { W = Wl0;  Bt = BtW0;  K = 256; Bcols = 256; t -= 49152; }
    else if (t < 81920) { W = Wl1;  Bt = BtW1;  K = 256; Bcols = 256; t -= 65536; }
    else return;
    int KS = K >> 5;
    int kg    = t & 7;
    int col   = (t >> 3) & 127;
    int rest  = t >> 10;
    int kstep = rest % KS;
    int ct    = rest / KS;
    int gcol  = ct * 128 + col;
    int kbase = kstep * 32 + kg * 4;
    uint4 v;
    v.x = packsplit(W[(size_t)(kbase + 0) * Bcols + gcol]);
    v.y = packsplit(W[(size_t)(kbase + 1) * Bcols + gcol]);
    v.z = packsplit(W[(size_t)(kbase + 2) * Bcols + gcol]);
    v.w = packsplit(W[(size_t)(kbase + 3) * Bcols + gcol]);
    size_t tile = (size_t)(ct * KS + kstep) * 8192;
    *(uint4*)&Bt[tile + col * 64 + ((kg * 8) ^ ((col & 7) << 3))] = v;
}

// ---------------------------------------------------------------------------
// Split-bf16 MFMA GEMM, tile 128x128, BK=32, 8 waves (2x4 of 64x32), dbuf.
// A loads NON-TEMPORAL. MODE=0 (layer): C is ushort* (fp16 h output).
// MODE=1 (upscale): fp32 gelu scatter via ci.
// ---------------------------------------------------------------------------
template<int MODE>
__global__ __launch_bounds__(512)
void gemm128(const float* __restrict__ A0, const float* __restrict__ A1,
             const ushort* __restrict__ B0, const ushort* __restrict__ B1,
             const float* __restrict__ bias0, const float* __restrict__ bias1,
             float* __restrict__ C, const int* __restrict__ ci,
             int M, int K, int cb0, int cb1)
{
    __shared__ ushort As[2][128 * 64];    // 16KB per buffer
    __shared__ ushort Bs[2][128 * 64];    // 16KB per buffer

    const int tid  = threadIdx.x;
    const int lane = tid & 63;
    const int w    = tid >> 6;            // 0..7
    const int wr   = w >> 2, wc = w & 3;  // wave -> 64x32 quadrant
    const int row0 = blockIdx.x * 128;
    const int KS   = K >> 5;

    const float* A; const ushort* Btile; const float* bias; int col_base, colt;
    if (MODE == 1) {
        int sel = blockIdx.y;
        A = sel ? A1 : A0; Btile = sel ? B1 : B0;
        bias = sel ? bias1 : bias0; col_base = sel ? cb1 : cb0; colt = 0;
    } else {
        A = A0; Btile = B0 + (size_t)blockIdx.y * KS * 8192;
        bias = nullptr; col_base = 0; colt = blockIdx.y * 128;
    }

    const int ar0 = tid >> 3;             // A row (p=0): 0..63
    const int ac4 = (tid & 7) * 4;        // A fp32 col within step

    f32x4 acc[4][2];
#pragma unroll
    for (int m = 0; m < 4; m++)
#pragma unroll
        for (int n = 0; n < 2; n++) acc[m][n] = (f32x4)0.f;

    auto loadA = [&](f32x4* rg, int ks) {
#pragma unroll
        for (int p = 0; p < 2; p++) {
            int gr = row0 + ar0 + p * 64;
            rg[p] = (f32x4)0.f;
            if (gr < M)
                rg[p] = __builtin_nontemporal_load(
                    (const f32x4*)&A[(size_t)gr * K + ks * 32 + ac4]);
        }
    };
    auto writeA = [&](int buf, const f32x4* rg) {
#pragma unroll
        for (int p = 0; p < 2; p++) {
            int r = ar0 + p * 64;
            uint4 wv;
            wv.x = packsplit(rg[p][0]); wv.y = packsplit(rg[p][1]);
            wv.z = packsplit(rg[p][2]); wv.w = packsplit(rg[p][3]);
            *(uint4*)&As[buf][r * 64 + ((2 * ac4) ^ ((r & 7) << 3))] = wv;
        }
    };
    auto stageB = [&](int buf, int ks) {
        const ushort* tp = Btile + (size_t)ks * 8192;
#pragma unroll
        for (int q = 0; q < 2; q++) {
            int off = (w * 2 + q) * 512;          // ushorts; 1KB per call
            __builtin_amdgcn_global_load_lds(
                (const __attribute__((address_space(1))) void*)(tp + off + lane * 8),
                (__attribute__((address_space(3))) void*)(&Bs[buf][off]),
                16, 0, 0);
        }
    };
    auto compute = [&](int buf) {
        bf16x8 af[4][2], bfr[2][2];
#pragma unroll
        for (int m = 0; m < 4; m++) {
            int row = wr * 64 + m * 16 + (lane & 15);
#pragma unroll
            for (int kb = 0; kb < 2; kb++) {
                int kp = kb * 32 + (lane >> 4) * 8;
                af[m][kb] = *(const bf16x8*)&As[buf][row * 64 + (kp ^ ((row & 7) << 3))];
            }
        }
#pragma unroll
        for (int n = 0; n < 2; n++) {
            int cq = wc * 32 + n * 16 + (lane & 15);
#pragma unroll
            for (int kb = 0; kb < 2; kb++) {
                int kp = kb * 32 + (lane >> 4) * 8;
                bfr[n][kb] = *(const bf16x8*)&Bs[buf][cq * 64 + (kp ^ ((cq & 7) << 3))];
            }
        }
#pragma unroll
        for (int m = 0; m < 4; m++)
#pragma unroll
            for (int n = 0; n < 2; n++) {
                acc[m][n] = __builtin_amdgcn_mfma_f32_16x16x32_bf16(
                    af[m][0], bfr[n][0], acc[m][n], 0, 0, 0);
                acc[m][n] = __builtin_amdgcn_mfma_f32_16x16x32_bf16(
                    af[m][1], bfr[n][1], acc[m][n], 0, 0, 0);
            }
    };

    // prologue: fill buffer 0, issue k=1 A loads
    f32x4 aprev[2];
    loadA(aprev, 0);
    stageB(0, 0);
    writeA(0, aprev);
    if (KS > 1) loadA(aprev, 1);
    __syncthreads();

    int cur = 0;
    for (int ks = 0; ks < KS - 1; ++ks) {
        int nxt = cur ^ 1;
        stageB(nxt, ks + 1);
        f32x4 anew[2];
        if (ks + 2 < KS) loadA(anew, ks + 2);
        writeA(nxt, aprev);
        compute(cur);
        __syncthreads();
        aprev[0] = anew[0]; aprev[1] = anew[1];
        cur = nxt;
    }
    compute(cur);

    // epilogue: C/D layout col=lane&15, row=(lane>>4)*4+reg
    ushort* C16 = (ushort*)C;
#pragma unroll
    for (int m = 0; m < 4; m++) {
        int rbase = row0 + wr * 64 + m * 16 + ((lane >> 4) << 2);
#pragma unroll
        for (int n = 0; n < 2; n++) {
            int col = wc * 32 + n * 16 + (lane & 15);
#pragma unroll
            for (int j = 0; j < 4; j++) {
                int grow = rbase + j;
                if (grow >= M) continue;
                float v = acc[m][n][j];
                if (MODE == 1) {
                    v = gelu_exact(v + bias[col]);
                    C[(size_t)ci[grow] * 256 + col_base + col] = v;
                } else {
                    C16[(size_t)grow * 256 + colt + col] = f2h(v);
                }
            }
        }
    }
}

// per-node attention scores (fp16 h input)
__global__ __launch_bounds__(256)
void scores_kernel(const ushort* __restrict__ h16, const float* __restrict__ asrc,
                   const float* __restrict__ adst, float* __restrict__ s_src,
                   float* __restrict__ s_dst, int N)
{
    int wave = threadIdx.x >> 6;
    int lane = threadIdx.x & 63;
    int n = blockIdx.x * 4 + wave;
    if (n >= N) return;
    ushort4 hv = *(const ushort4*)&h16[(size_t)n * 256 + lane * 4];
    float x0 = h2f(hv.x), x1 = h2f(hv.y), x2 = h2f(hv.z), x3 = h2f(hv.w);
    float4 av = *(const float4*)&asrc[lane * 4];
    float4 dv = *(const float4*)&adst[lane * 4];
    float ps = x0 * av.x + x1 * av.y + x2 * av.z + x3 * av.w;
    float pd = x0 * dv.x + x1 * dv.y + x2 * dv.z + x3 * dv.w;
#pragma unroll
    for (int off = 32; off; off >>= 1) {
        ps += __shfl_xor(ps, off);
        pd += __shfl_xor(pd, off);
    }
    if (lane == 0) { s_src[n] = ps; s_dst[n] = pd; }
}

// ---- CSR build (5 launches) ----
__global__ void count_edges(const int* __restrict__ edges, int* cnt, int E) {
    int e = blockIdx.x * 256 + threadIdx.x;
    if (e < E) atomicAdd(&cnt[edges[2 * e + 1]], 1);
}

__global__ void scan1(const int* __restrict__ cnt, int* __restrict__ rs,
                      int* __restrict__ bsum, int N)
{
    __shared__ int sm[256];
    int tid = threadIdx.x;
    int i = blockIdx.x * 256 + tid;
    int v = (i < N) ? (cnt[i] + 1) : 0;
    sm[tid] = v;
    __syncthreads();
    for (int off = 1; off < 256; off <<= 1) {
        int t = (tid >= off) ? sm[tid - off] : 0;
        __syncthreads();
        sm[tid] += t;
        __syncthreads();
    }
    if (i < N) rs[i] = sm[tid] - v;
    if (tid == 255) bsum[blockIdx.x] = sm[255];
}

__global__ void scan2(int* bsum, int nb) {
    __shared__ int sm[256];
    int tid = threadIdx.x;
    int v = (tid < nb) ? bsum[tid] : 0;
    sm[tid] = v;
    __syncthreads();
    for (int off = 1; off < 256; off <<= 1) {
        int t = (tid >= off) ? sm[tid - off] : 0;
        __syncthreads();
        sm[tid] += t;
        __syncthreads();
    }
    if (tid < nb) bsum[tid] = sm[tid] - v;
}

__global__ void scan3(int* __restrict__ rs, const int* __restrict__ bsum,
                      int* __restrict__ cur, int N, int total)
{
    int i = blockIdx.x * 256 + threadIdx.x;
    if (i < N) {
        int v = rs[i] + bsum[i >> 8];
        rs[i] = v;
        cur[i] = v;
    }
    if (i == 0) rs[N] = total;
}

__global__ void fill_csr(const int* __restrict__ edges, int* __restrict__ cur,
                         int* __restrict__ col, int E, int N)
{
    int i = blockIdx.x * 256 + threadIdx.x;
    if (i < E) {
        int s = edges[2 * i], d = edges[2 * i + 1];
        col[atomicAdd(&cur[d], 1)] = s;
    } else if (i < E + N) {
        int n = i - E;
        col[atomicAdd(&cur[n], 1)] = n;
    }
}

// ---------------------------------------------------------------------------
// attn: WAVE per dst node. No LDS, no barriers. fp16 h gather (ushort4/lane).
// ---------------------------------------------------------------------------
template<int EPI>
__global__ __launch_bounds__(256)
void attn_kernel(const ushort* __restrict__ h16, const float* __restrict__ s_src,
                 const float* __restrict__ s_dst, const int* __restrict__ rs,
                 const int* __restrict__ colv, const float* __restrict__ bias,
                 float* __restrict__ out, int N)
{
    const int wv   = threadIdx.x >> 6;
    const int lane = threadIdx.x & 63;
    const int n    = blockIdx.x * 4 + wv;
    if (n >= N) return;

    const float sd = s_dst[n];
    const int beg = rs[n], end = rs[n + 1];

    float4 acc = make_float4(0.f, 0.f, 0.f, 0.f);
    float den = 0.f;

    int i = beg;
    for (; i + 3 < end; i += 4) {
        int s0 = colv[i], s1 = colv[i + 1], s2 = colv[i + 2], s3 = colv[i + 3];
        float e0 = s_src[s0] + sd, e1 = s_src[s1] + sd;
        float e2 = s_src[s2] + sd, e3 = s_src[s3] + sd;
        e0 = (e0 > 0.f) ? e0 : 0.2f * e0;  e1 = (e1 > 0.f) ? e1 : 0.2f * e1;
        e2 = (e2 > 0.f) ? e2 : 0.2f * e2;  e3 = (e3 > 0.f) ? e3 : 0.2f * e3;
        float w0 = __expf(e0), w1 = __expf(e1), w2 = __expf(e2), w3 = __expf(e3);
        ushort4 u0 = *(const ushort4*)&h16[(size_t)s0 * 256 + lane * 4];
        ushort4 u1 = *(const ushort4*)&h16[(size_t)s1 * 256 + lane * 4];
        ushort4 u2 = *(const ushort4*)&h16[(size_t)s2 * 256 + lane * 4];
        ushort4 u3 = *(const ushort4*)&h16[(size_t)s3 * 256 + lane * 4];
        acc.x = fmaf(w0, h2f(u0.x), acc.x); acc.y = fmaf(w0, h2f(u0.y), acc.y);
        acc.z = fmaf(w0, h2f(u0.z), acc.z); acc.w = fmaf(w0, h2f(u0.w), acc.w);
        acc.x = fmaf(w1, h2f(u1.x), acc.x); acc.y = fmaf(w1, h2f(u1.y), acc.y);
        acc.z = fmaf(w1, h2f(u1.z), acc.z); acc.w = fmaf(w1, h2f(u1.w), acc.w);
        acc.x = fmaf(w2, h2f(u2.x), acc.x); acc.y = fmaf(w2, h2f(u2.y), acc.y);
        acc.z = fmaf(w2, h2f(u2.z), acc.z); acc.w = fmaf(w2, h2f(u2.w), acc.w);
        acc.x = fmaf(w3, h2f(u3.x), acc.x); acc.y = fmaf(w3, h2f(u3.y), acc.y);
        acc.z = fmaf(w3, h2f(u3.z), acc.z); acc.w = fmaf(w3, h2f(u3.w), acc.w);
        den += w0 + w1 + w2 + w3;
    }
    for (; i < end; ++i) {
        int s0 = colv[i];
        float e0 = s_src[s0] + sd;
        e0 = (e0 > 0.f) ? e0 : 0.2f * e0;
        float w0 = __expf(e0);
        ushort4 u0 = *(const ushort4*)&h16[(size_t)s0 * 256 + lane * 4];
        acc.x = fmaf(w0, h2f(u0.x), acc.x); acc.y = fmaf(w0, h2f(u0.y), acc.y);
        acc.z = fmaf(w0, h2f(u0.z), acc.z); acc.w = fmaf(w0, h2f(u0.w), acc.w);
        den += w0;
    }

    float4 bv = *(const float4*)&bias[lane * 4];
    float inv = 1.f / den;
    float4 v;
    v.x = acc.x * inv + bv.x; v.y = acc.y * inv + bv.y;
    v.z = acc.z * inv + bv.z; v.w = acc.w * inv + bv.w;
    if (EPI == 1) {
        v.x = gelu_exact(v.x); v.y = gelu_exact(v.y);
        v.z = gelu_exact(v.z); v.w = gelu_exact(v.w);
    } else {
        v.x = fmaxf(v.x, 0.f); v.y = fmaxf(v.y, 0.f);
        v.z = fmaxf(v.z, 0.f); v.w = fmaxf(v.w, 0.f);
    }
    *(float4*)&out[(size_t)n * 256 + lane * 4] = v;
}

extern "C" void kernel_launch(void* const* d_in, const int* in_sizes, int n_in,
                              void* d_out, int out_size, void* d_ws, size_t ws_size,
                              hipStream_t stream)
{
    const float* img    = (const float*)d_in[0];
    const float* txt    = (const float*)d_in[1];
    const int*   ci     = (const int*)d_in[2];
    const int*   edges  = (const int*)d_in[3];
    const float* w_img  = (const float*)d_in[4];
    const float* b_img  = (const float*)d_in[5];
    const float* w_text = (const float*)d_in[6];
    const float* b_text = (const float*)d_in[7];
    const float* W0     = (const float*)d_in[8];
    const float* asrc0  = (const float*)d_in[9];
    const float* adst0  = (const float*)d_in[10];
    const float* bias0  = (const float*)d_in[11];
    const float* W1     = (const float*)d_in[12];
    const float* asrc1  = (const float*)d_in[13];
    const float* adst1  = (const float*)d_in[14];
    const float* bias1  = (const float*)d_in[15];

    const int N = in_sizes[2];
    const int E = in_sizes[3] / 2;
    const int T = E + N;

    // workspace layout
    float*  fA  = (float*)d_ws;                    // node / attn0 out  N*256 f32
    float*  fB  = fA + (size_t)N * 256;            // h16 (ushort view) N*256
    float*  sS  = fB + (size_t)N * 256;            // N
    float*  sD  = sS + N;                          // N
    int*    rs  = (int*)(sD + N);                  // N+1
    int*    cur = rs + (N + 1);                    // N
    int*    col = cur + N;                         // E+N
    int*    bsum = col + T;                        // <=256
    uintptr_t bt0 = ((uintptr_t)(bsum + 256) + 63) & ~(uintptr_t)63;
    ushort* BtImg = (ushort*)bt0;                  // 24 tiles x 8192
    ushort* BtTxt = BtImg + 24 * 8192;
    ushort* BtW0  = BtTxt + 24 * 8192;             // 16 tiles x 8192
    ushort* BtW1  = BtW0  + 16 * 8192;
    ushort* h16 = (ushort*)fB;

    const int nb256 = (N + 255) / 256;
    const int nbT   = (T + 255) / 256;
    const int gm128 = (N + 127) / 128;             // 391

    conv_all<<<(81920 + 255) / 256, 256, 0, stream>>>(
        w_img, w_text, W0, W1, BtImg, BtTxt, BtW0, BtW1);

    (void)hipMemsetAsync(cur, 0, (size_t)N * sizeof(int), stream);

    // merged upscale GEMMs: node -> fA (fp32)
    gemm128<1><<<dim3(gm128, 2), 512, 0, stream>>>(
        img, txt, BtImg, BtTxt, b_img, b_text, fA, ci, N, 768, 0, 128);

    count_edges<<<(E + 255) / 256, 256, 0, stream>>>(edges, cur, E);
    scan1<<<nb256, 256, 0, stream>>>(cur, rs, bsum, N);
    scan2<<<1, 256, 0, stream>>>(bsum, nb256);
    scan3<<<nb256, 256, 0, stream>>>(rs, bsum, cur, N, T);
    fill_csr<<<nbT, 256, 0, stream>>>(edges, cur, col, E, N);

    // ---- layer 0: h16 <- fA @ W0 ; attn0 -> fA (node is dead) ----
    gemm128<0><<<dim3(gm128, 2), 512, 0, stream>>>(
        fA, nullptr, BtW0, nullptr, nullptr, nullptr, fB, nullptr, N, 256, 0, 0);
    scores_kernel<<<(N + 3) / 4, 256, 0, stream>>>(h16, asrc0, adst0, sS, sD, N);
    attn_kernel<0><<<(N + 3) / 4, 256, 0, stream>>>(h16, sS, sD, rs, col, bias0, fA, N);

    // ---- layer 1: h16 <- fA @ W1 ; attn1 -> d_out ----
    gemm128<0><<<dim3(gm128, 2), 512, 0, stream>>>(
        fA, nullptr, BtW1, nullptr, nullptr, nullptr, fB, nullptr, N, 256, 0, 0);
    scores_kernel<<<(N + 3) / 4, 256, 0, stream>>>(h16, asrc1, adst1, sS, sD, N);
    attn_kernel<1><<<(N + 3) / 4, 256, 0, stream>>>(h16, sS, sD, rs, col, bias1, (float*)d_out, N);
}